// Round 1
// baseline (464.922 us; speedup 1.0000x reference)
//
#include <hip/hip_runtime.h>
#include <math.h>

// Top-1 MoE: only the argmax expert per token is computed.
// Gate in fp32 (argmax stability); experts 0/1 via grouped bf16 MFMA GEMMs;
// experts 2-5 are cheap per-token kernels.
//
// Workspace layout (~63.1 MB): counts | scale | token lists | bf16 W^T x4 | h1 | h2

#define E 1024
#define GH 256
#define NEXP 6
#define NTOK 8192

typedef __attribute__((ext_vector_type(8))) short bf16x8;
typedef __attribute__((ext_vector_type(4))) float f32x4;

__device__ __forceinline__ float gelu_erf(float v) {
    return 0.5f * v * (1.0f + erff(v * 0.70710678118654752440f));
}

__device__ __forceinline__ short f2bf(float f) {
    union { float f; unsigned u; } c; c.f = f;
    unsigned u = c.u;
    u += 0x7fffu + ((u >> 16) & 1u);   // round-to-nearest-even
    return (short)(u >> 16);
}

// ---------------- weight transpose + fp32->bf16:  src[R][C] -> dst[C][R] ----
__global__ __launch_bounds__(256)
void transpose_bf16_kernel(const float* __restrict__ src, short* __restrict__ dst,
                           int R, int C) {
    __shared__ float tile[32][33];
    const int tx = threadIdx.x & 31, ty = threadIdx.x >> 5;
    const int c0 = blockIdx.x * 32, r0 = blockIdx.y * 32;
#pragma unroll
    for (int i = 0; i < 4; ++i)
        tile[ty + i * 8][tx] = src[(size_t)(r0 + ty + i * 8) * C + c0 + tx];
    __syncthreads();
#pragma unroll
    for (int i = 0; i < 4; ++i)
        dst[(size_t)(c0 + ty + i * 8) * R + r0 + tx] = f2bf(tile[tx][ty + i * 8]);
}

// ---------------- fused fp32 gate: logits -> softmax -> argmax -> scatter ---
__global__ __launch_bounds__(256)
void gate_kernel(const float* __restrict__ x,
                 const float* __restrict__ gw1, const float* __restrict__ gb1,
                 const float* __restrict__ gw2, const float* __restrict__ gb2,
                 const float* __restrict__ ebias, const float* __restrict__ pm_alpha,
                 float* __restrict__ scale, int* __restrict__ counts,
                 int* __restrict__ tlist) {
    __shared__ float Xs[32][33];
    __shared__ float WH[32 * 257];   // W phase: [32][256] stride 256; H phase: stride 257
    __shared__ float Ls[32][8];
    const int tid = threadIdx.x;
    const int t0 = blockIdx.x * 32;
    const int c  = tid & 31;   // cols c*8 .. c*8+7
    const int tg = tid >> 5;   // tokens tg*4 .. tg*4+3

    float acc[4][8];
#pragma unroll
    for (int i = 0; i < 4; ++i)
#pragma unroll
        for (int j = 0; j < 8; ++j) acc[i][j] = 0.f;

    const int xt = tid >> 3, xk = (tid & 7) * 4;
    for (int k0 = 0; k0 < E; k0 += 32) {
        float4 xv = *reinterpret_cast<const float4*>(&x[(size_t)(t0 + xt) * E + k0 + xk]);
        Xs[xt][xk] = xv.x; Xs[xt][xk + 1] = xv.y; Xs[xt][xk + 2] = xv.z; Xs[xt][xk + 3] = xv.w;
#pragma unroll
        for (int j = 0; j < 8; ++j) {
            int kk = (tid >> 6) + j * 4;
            int col = (tid & 63) * 4;
            *reinterpret_cast<float4*>(&WH[kk * GH + col]) =
                *reinterpret_cast<const float4*>(&gw1[(size_t)(k0 + kk) * GH + col]);
        }
        __syncthreads();
#pragma unroll 8
        for (int kk = 0; kk < 32; ++kk) {
            float xr[4];
#pragma unroll
            for (int i = 0; i < 4; ++i) xr[i] = Xs[tg * 4 + i][kk];
            float wr[8];
            *reinterpret_cast<float4*>(&wr[0]) = *reinterpret_cast<float4*>(&WH[kk * GH + c * 8]);
            *reinterpret_cast<float4*>(&wr[4]) = *reinterpret_cast<float4*>(&WH[kk * GH + c * 8 + 4]);
#pragma unroll
            for (int i = 0; i < 4; ++i)
#pragma unroll
                for (int j = 0; j < 8; ++j) acc[i][j] += xr[i] * wr[j];
        }
        __syncthreads();
    }
    // h = gelu(acc + gb1) into WH (stride 257)
#pragma unroll
    for (int i = 0; i < 4; ++i)
#pragma unroll
        for (int j = 0; j < 8; ++j) {
            int col = c * 8 + j;
            WH[(tg * 4 + i) * 257 + col] = gelu_erf(acc[i][j] + gb1[col]);
        }
    __syncthreads();
    if (tid < 192) {
        int t = tid & 31, m = tid >> 5;
        float s = gb2[m] + ebias[m];
        for (int k = 0; k < GH; ++k) s += WH[t * 257 + k] * gw2[k * NEXP + m];
        Ls[t][m] = s;
    }
    __syncthreads();
    if (tid < 32) {
        int t = tid;
        float mx = Ls[t][0]; int am = 0;
#pragma unroll
        for (int m = 1; m < NEXP; ++m) { float v = Ls[t][m]; if (v > mx) { mx = v; am = m; } }
        float S = 0.f;
#pragma unroll
        for (int m = 0; m < NEXP; ++m) S += expf(Ls[t][m] - mx);
        float pt = 1.f / S;                 // top-1 softmax prob
        float w = pt / (pt + 1e-9f);        // renormalized top-1 weight
        scale[t0 + t] = pm_alpha[0] * w;
        int pos = atomicAdd(&counts[am], 1);
        tlist[am * NTOK + pos] = t0 + t;
    }
}

// ---------------- grouped bf16 MFMA GEMM, 64x64 tile, BK=32 -----------------
// A: gathered fp32 x rows (GATHER_A) or bf16 h buffer (group-ordered).
// B: pre-transposed bf16 [N][K].  EPI_GELU: gelu -> bf16 Hout; else scale->Cout.
template <bool GATHER_A, bool EPI_GELU>
__global__ __launch_bounds__(256)
void moe_gemm_kernel(const float* __restrict__ Afp, const short* __restrict__ Abf,
                     const short* __restrict__ Bt, const float* __restrict__ bias,
                     const int* __restrict__ counts, int eidx,
                     const int* __restrict__ tlist, const float* __restrict__ scale,
                     short* __restrict__ Hout, float* __restrict__ Cout,
                     int K, int N) {
    const int n_rows = counts[eidx];
    const int i0 = blockIdx.y * 64;
    if (i0 >= n_rows) return;
    const int rows = min(64, n_rows - i0);
    const int n0 = blockIdx.x * 64;

    __shared__ __align__(16) short As[64 * 40];   // row stride 40 (80B, 16B-aligned)
    __shared__ __align__(16) short Bs[64 * 40];
    __shared__ int toks[64];
    const int tid = threadIdx.x;
    if (tid < 64) toks[tid] = tlist[eidx * NTOK + i0 + min(tid, rows - 1)];
    __syncthreads();

    f32x4 acc[2][2];
#pragma unroll
    for (int s = 0; s < 2; ++s)
#pragma unroll
        for (int t = 0; t < 2; ++t) acc[s][t] = (f32x4){0.f, 0.f, 0.f, 0.f};

    const int lane = tid & 63, wv = tid >> 6;
    const int wm = (wv & 1) * 32, wn = (wv >> 1) * 32;
    const int lm = lane & 15, q = lane >> 4;
    const int sr = tid >> 2, skg = (tid & 3) * 8;

    for (int k0 = 0; k0 < K; k0 += 32) {
        if constexpr (GATHER_A) {
            const float* src = Afp + (size_t)toks[sr] * K + k0 + skg;
            float4 v0 = *reinterpret_cast<const float4*>(src);
            float4 v1 = *reinterpret_cast<const float4*>(src + 4);
            short tmp[8] = { f2bf(v0.x), f2bf(v0.y), f2bf(v0.z), f2bf(v0.w),
                             f2bf(v1.x), f2bf(v1.y), f2bf(v1.z), f2bf(v1.w) };
            *reinterpret_cast<bf16x8*>(&As[sr * 40 + skg]) = *reinterpret_cast<bf16x8*>(tmp);
        } else {
            int rr = i0 + min(sr, rows - 1);
            *reinterpret_cast<bf16x8*>(&As[sr * 40 + skg]) =
                *reinterpret_cast<const bf16x8*>(&Abf[(size_t)rr * K + k0 + skg]);
        }
        *reinterpret_cast<bf16x8*>(&Bs[sr * 40 + skg]) =
            *reinterpret_cast<const bf16x8*>(&Bt[(size_t)(n0 + sr) * K + k0 + skg]);
        __syncthreads();
        bf16x8 af[2], bfr[2];
#pragma unroll
        for (int s = 0; s < 2; ++s) {
            af[s]  = *reinterpret_cast<bf16x8*>(&As[(wm + s * 16 + lm) * 40 + q * 8]);
            bfr[s] = *reinterpret_cast<bf16x8*>(&Bs[(wn + s * 16 + lm) * 40 + q * 8]);
        }
#pragma unroll
        for (int s = 0; s < 2; ++s)
#pragma unroll
            for (int t = 0; t < 2; ++t)
                acc[s][t] = __builtin_amdgcn_mfma_f32_16x16x32_bf16(af[s], bfr[t], acc[s][t], 0, 0, 0);
        __syncthreads();
    }
    // epilogue: C/D mapping col=lane&15, row=(lane>>4)*4+reg (m89/m91-verified)
#pragma unroll
    for (int s = 0; s < 2; ++s)
#pragma unroll
        for (int t = 0; t < 2; ++t)
#pragma unroll
            for (int rg = 0; rg < 4; ++rg) {
                int rl = wm + s * 16 + q * 4 + rg;
                if (rl < rows) {
                    int gc = n0 + wn + t * 16 + lm;
                    float v = acc[s][t][rg] + bias[gc];
                    if constexpr (EPI_GELU) {
                        Hout[(size_t)(i0 + rl) * N + gc] = f2bf(gelu_erf(v));
                    } else {
                        int tok = toks[rl];
                        Cout[(size_t)tok * N + gc] = scale[tok] * v;
                    }
                }
            }
}

// ---------------- cheap experts (2: rank2, 3: rank4, 4: ReGLU1D, 5: FiLM) ---
__global__ __launch_bounds__(256)
void cheap_experts_kernel(const float* __restrict__ x,
                          const int* __restrict__ counts, const int* __restrict__ tlist,
                          const float* __restrict__ scale,
                          const float* __restrict__ p2_w, const float* __restrict__ p2_v,
                          const float* __restrict__ p2_alpha, const float* __restrict__ p2_b,
                          const float* __restrict__ p2_bias,
                          const float* __restrict__ p4_w, const float* __restrict__ p4_v,
                          const float* __restrict__ p4_alpha, const float* __restrict__ p4_b,
                          const float* __restrict__ p4_bias,
                          const float* __restrict__ rg_u, const float* __restrict__ rg_a,
                          const float* __restrict__ rg_b, const float* __restrict__ rg_bias,
                          const float* __restrict__ fl_dw, const float* __restrict__ fl_db,
                          const float* __restrict__ fl_uw, const float* __restrict__ fl_ub,
                          float* __restrict__ out) {
    const int e = 2 + blockIdx.y;
    const int i = blockIdx.x;
    if (i >= counts[e]) return;
    const int tok = tlist[e * NTOK + i];
    __shared__ float xs[E];
    __shared__ float red[16][4];
    __shared__ float gs[16];
    const int tid = threadIdx.x;
    *reinterpret_cast<float4*>(&xs[tid * 4]) =
        *reinterpret_cast<const float4*>(&x[(size_t)tok * E + tid * 4]);
    __syncthreads();
    const float sc = scale[tok];
    const int lane = tid & 63, wid = tid >> 6;

    if (e == 2 || e == 3) {
        const int n = (e == 2) ? 2 : 4;
        const float* w    = (e == 2) ? p2_w : p4_w;
        const float* v    = (e == 2) ? p2_v : p4_v;
        const float* al   = (e == 2) ? p2_alpha : p4_alpha;
        const float* b    = (e == 2) ? p2_b : p4_b;
        const float* bias = (e == 2) ? p2_bias : p4_bias;
        float p[4] = {0.f, 0.f, 0.f, 0.f};
        for (int k = tid; k < E; k += 256) {
            float xv = xs[k];
            for (int j = 0; j < n; ++j) p[j] += xv * w[j * E + k];
        }
        for (int j = 0; j < n; ++j) {
            float val = p[j];
            for (int off = 32; off > 0; off >>= 1) val += __shfl_down(val, off, 64);
            if (lane == 0) red[j][wid] = val;
        }
        __syncthreads();
        if (tid < n) {
            float s = red[tid][0] + red[tid][1] + red[tid][2] + red[tid][3] + b[tid];
            gs[tid] = al[tid] * gelu_erf(s);
        }
        __syncthreads();
        for (int cx = tid; cx < E; cx += 256) {
            float o = bias[cx];
            for (int j = 0; j < n; ++j) o += gs[j] * v[j * E + cx];
            out[(size_t)tok * E + cx] = sc * o;
        }
    } else if (e == 4) {
        float pv = 0.f;
        for (int k = tid; k < E; k += 256) pv += xs[k] * rg_u[k];
        for (int off = 32; off > 0; off >>= 1) pv += __shfl_down(pv, off, 64);
        if (lane == 0) red[0][wid] = pv;
        __syncthreads();
        float s = red[0][0] + red[0][1] + red[0][2] + red[0][3] + rg_b[0];
        float sg = 1.f / (1.f + expf(-s));
        for (int cx = tid; cx < E; cx += 256)
            out[(size_t)tok * E + cx] = sc * (sg * xs[cx] * rg_a[cx] + rg_bias[cx]);
    } else {  // FiLM
        float p[16];
#pragma unroll
        for (int j = 0; j < 16; ++j) p[j] = 0.f;
        for (int k = tid; k < E; k += 256) {
            float xv = xs[k];
            const float* wr = &fl_dw[k * 16];
#pragma unroll
            for (int j = 0; j < 16; ++j) p[j] += xv * wr[j];
        }
#pragma unroll
        for (int j = 0; j < 16; ++j) {
            float val = p[j];
            for (int off = 32; off > 0; off >>= 1) val += __shfl_down(val, off, 64);
            if (lane == 0) red[j][wid] = val;
        }
        __syncthreads();
        if (tid < 16)
            gs[tid] = gelu_erf(red[tid][0] + red[tid][1] + red[tid][2] + red[tid][3] + fl_db[tid]);
        __syncthreads();
        for (int cx = tid; cx < E; cx += 256) {
            float ga = fl_ub[cx], be = fl_ub[E + cx];
#pragma unroll
            for (int j = 0; j < 16; ++j) {
                float tj = gs[j];
                ga += tj * fl_uw[j * 2 * E + cx];
                be += tj * fl_uw[j * 2 * E + E + cx];
            }
            out[(size_t)tok * E + cx] = sc * (ga * xs[cx] + be);
        }
    }
}

extern "C" void kernel_launch(void* const* d_in, const int* in_sizes, int n_in,
                              void* d_out, int out_size, void* d_ws, size_t ws_size,
                              hipStream_t stream) {
    const float* x        = (const float*)d_in[0];
    const float* gw1      = (const float*)d_in[1];
    const float* gb1      = (const float*)d_in[2];
    const float* gw2      = (const float*)d_in[3];
    const float* gb2      = (const float*)d_in[4];
    const float* ebias    = (const float*)d_in[5];
    const float* pm_alpha = (const float*)d_in[6];
    const float* dfc_w    = (const float*)d_in[7];
    const float* dfc_b    = (const float*)d_in[8];
    const float* dproj_w  = (const float*)d_in[9];
    const float* dproj_b  = (const float*)d_in[10];
    const float* sfc_w    = (const float*)d_in[11];
    const float* sfc_b    = (const float*)d_in[12];
    const float* sproj_w  = (const float*)d_in[13];
    const float* sproj_b  = (const float*)d_in[14];
    const float* p2_w     = (const float*)d_in[15];
    const float* p2_v     = (const float*)d_in[16];
    const float* p2_alpha = (const float*)d_in[17];
    const float* p2_b     = (const float*)d_in[18];
    const float* p2_bias  = (const float*)d_in[19];
    const float* p4_w     = (const float*)d_in[20];
    const float* p4_v     = (const float*)d_in[21];
    const float* p4_alpha = (const float*)d_in[22];
    const float* p4_b     = (const float*)d_in[23];
    const float* p4_bias  = (const float*)d_in[24];
    const float* rg_u     = (const float*)d_in[25];
    const float* rg_a     = (const float*)d_in[26];
    const float* rg_b     = (const float*)d_in[27];
    const float* rg_bias  = (const float*)d_in[28];
    const float* fl_dw    = (const float*)d_in[29];
    const float* fl_db    = (const float*)d_in[30];
    const float* fl_uw    = (const float*)d_in[31];
    const float* fl_ub    = (const float*)d_in[32];
    float* out = (float*)d_out;

    char* ws = (char*)d_ws;
    size_t off = 0;
    int*   counts   = (int*)(ws + off);   off += 256;
    float* scale    = (float*)(ws + off); off += (size_t)NTOK * 4;
    int*   tlist    = (int*)(ws + off);   off += (size_t)NEXP * NTOK * 4;
    short* dfc_wt   = (short*)(ws + off); off += (size_t)2048 * 1024 * 2;
    short* dproj_wt = (short*)(ws + off); off += (size_t)1024 * 2048 * 2;
    short* sfc_wt   = (short*)(ws + off); off += (size_t)1024 * 1024 * 2;
    short* sproj_wt = (short*)(ws + off); off += (size_t)1024 * 1024 * 2;
    short* h1       = (short*)(ws + off); off += (size_t)NTOK * 2048 * 2;
    short* h2       = (short*)(ws + off); off += (size_t)NTOK * 1024 * 2;  // ~63.1 MB total

    hipMemsetAsync(counts, 0, 256, stream);
    transpose_bf16_kernel<<<dim3(2048 / 32, 1024 / 32), 256, 0, stream>>>(dfc_w, dfc_wt, 1024, 2048);
    transpose_bf16_kernel<<<dim3(1024 / 32, 2048 / 32), 256, 0, stream>>>(dproj_w, dproj_wt, 2048, 1024);
    transpose_bf16_kernel<<<dim3(1024 / 32, 1024 / 32), 256, 0, stream>>>(sfc_w, sfc_wt, 1024, 1024);
    transpose_bf16_kernel<<<dim3(1024 / 32, 1024 / 32), 256, 0, stream>>>(sproj_w, sproj_wt, 1024, 1024);
    gate_kernel<<<NTOK / 32, 256, 0, stream>>>(x, gw1, gb1, gw2, gb2, ebias, pm_alpha,
                                               scale, counts, tlist);
    moe_gemm_kernel<true, true><<<dim3(2048 / 64, NTOK / 64), 256, 0, stream>>>(
        x, nullptr, dfc_wt, dfc_b, counts, 0, tlist, scale, h1, nullptr, 1024, 2048);
    moe_gemm_kernel<true, true><<<dim3(1024 / 64, NTOK / 64), 256, 0, stream>>>(
        x, nullptr, sfc_wt, sfc_b, counts, 1, tlist, scale, h2, nullptr, 1024, 1024);
    moe_gemm_kernel<false, false><<<dim3(1024 / 64, NTOK / 64), 256, 0, stream>>>(
        nullptr, h1, dproj_wt, dproj_b, counts, 0, tlist, scale, nullptr, out, 2048, 1024);
    moe_gemm_kernel<false, false><<<dim3(1024 / 64, NTOK / 64), 256, 0, stream>>>(
        nullptr, h2, sproj_wt, sproj_b, counts, 1, tlist, scale, nullptr, out, 1024, 1024);
    cheap_experts_kernel<<<dim3(NTOK, 4), 256, 0, stream>>>(
        x, counts, tlist, scale,
        p2_w, p2_v, p2_alpha, p2_b, p2_bias,
        p4_w, p4_v, p4_alpha, p4_b, p4_bias,
        rg_u, rg_a, rg_b, rg_bias,
        fl_dw, fl_db, fl_uw, fl_ub, out);
    (void)in_sizes; (void)n_in; (void)out_size; (void)ws_size;
}

// Round 2
// 438.663 us; speedup vs baseline: 1.0599x; 1.0599x over previous
//
#include <hip/hip_runtime.h>
#include <math.h>

// Top-1 MoE: only the argmax expert per token is computed.
// Gate in fp32 (argmax stability): tiled GEMM1 (x@gw1, gelu) + tiny logits kernel.
// Experts 0/1 via grouped bf16 MFMA GEMMs; experts 2-5 cheap per-token kernels.

#define E 1024
#define GH 256
#define NEXP 6
#define NTOK 8192

typedef __attribute__((ext_vector_type(8))) short bf16x8;
typedef __attribute__((ext_vector_type(4))) float f32x4;

__device__ __forceinline__ float gelu_erf(float v) {
    return 0.5f * v * (1.0f + erff(v * 0.70710678118654752440f));
}

__device__ __forceinline__ short f2bf(float f) {
    union { float f; unsigned u; } c; c.f = f;
    unsigned u = c.u;
    u += 0x7fffu + ((u >> 16) & 1u);   // round-to-nearest-even
    return (short)(u >> 16);
}

// ---------------- weight transpose + fp32->bf16:  src[R][C] -> dst[C][R] ----
__global__ __launch_bounds__(256)
void transpose_bf16_kernel(const float* __restrict__ src, short* __restrict__ dst,
                           int R, int C) {
    __shared__ float tile[32][33];
    const int tx = threadIdx.x & 31, ty = threadIdx.x >> 5;
    const int c0 = blockIdx.x * 32, r0 = blockIdx.y * 32;
#pragma unroll
    for (int i = 0; i < 4; ++i)
        tile[ty + i * 8][tx] = src[(size_t)(r0 + ty + i * 8) * C + c0 + tx];
    __syncthreads();
#pragma unroll
    for (int i = 0; i < 4; ++i)
        dst[(size_t)(c0 + ty + i * 8) * R + r0 + tx] = f2bf(tile[tx][ty + i * 8]);
}

// ---------------- gate GEMM1: h = gelu(x @ gw1 + gb1), fp32 ----------------
// 64x64 tile, BK=32, 4x4 register blocking. Grid (GH/64, NTOK/64) = 512 blocks.
__global__ __launch_bounds__(256)
void gate_gemm1_kernel(const float* __restrict__ x, const float* __restrict__ gw1,
                       const float* __restrict__ gb1, float* __restrict__ h) {
    __shared__ float As[32][68];   // [k][m], pad to 68 (16B-aligned rows, <=2-way banks)
    __shared__ float Bs[32][68];   // [k][n]
    const int tid = threadIdx.x;
    const int t0 = blockIdx.y * 64, n0 = blockIdx.x * 64;
    const int tx = tid & 15, ty = tid >> 4;          // out tile: rows ty*4.., cols tx*4..
    const int am = tid >> 2, ak = (tid & 3) * 8;     // A stage: row am, k ak..ak+7
    const int bk = tid >> 3, bn = (tid & 7) * 8;     // B stage: k bk, cols bn..bn+7

    float acc[4][4];
#pragma unroll
    for (int i = 0; i < 4; ++i)
#pragma unroll
        for (int j = 0; j < 4; ++j) acc[i][j] = 0.f;

    for (int k0 = 0; k0 < E; k0 += 32) {
        float4 a0 = *reinterpret_cast<const float4*>(&x[(size_t)(t0 + am) * E + k0 + ak]);
        float4 a1 = *reinterpret_cast<const float4*>(&x[(size_t)(t0 + am) * E + k0 + ak + 4]);
        float4 b0 = *reinterpret_cast<const float4*>(&gw1[(size_t)(k0 + bk) * GH + n0 + bn]);
        float4 b1 = *reinterpret_cast<const float4*>(&gw1[(size_t)(k0 + bk) * GH + n0 + bn + 4]);
        __syncthreads();
        As[ak + 0][am] = a0.x; As[ak + 1][am] = a0.y; As[ak + 2][am] = a0.z; As[ak + 3][am] = a0.w;
        As[ak + 4][am] = a1.x; As[ak + 5][am] = a1.y; As[ak + 6][am] = a1.z; As[ak + 7][am] = a1.w;
        *reinterpret_cast<float4*>(&Bs[bk][bn])     = b0;
        *reinterpret_cast<float4*>(&Bs[bk][bn + 4]) = b1;
        __syncthreads();
#pragma unroll
        for (int kk = 0; kk < 32; ++kk) {
            float a[4], b[4];
            *reinterpret_cast<float4*>(a) = *reinterpret_cast<float4*>(&As[kk][ty * 4]);
            *reinterpret_cast<float4*>(b) = *reinterpret_cast<float4*>(&Bs[kk][tx * 4]);
#pragma unroll
            for (int i = 0; i < 4; ++i)
#pragma unroll
                for (int j = 0; j < 4; ++j) acc[i][j] += a[i] * b[j];
        }
    }
#pragma unroll
    for (int i = 0; i < 4; ++i) {
        float4 o;
        o.x = gelu_erf(acc[i][0] + gb1[n0 + tx * 4 + 0]);
        o.y = gelu_erf(acc[i][1] + gb1[n0 + tx * 4 + 1]);
        o.z = gelu_erf(acc[i][2] + gb1[n0 + tx * 4 + 2]);
        o.w = gelu_erf(acc[i][3] + gb1[n0 + tx * 4 + 3]);
        *reinterpret_cast<float4*>(&h[(size_t)(t0 + ty * 4 + i) * GH + n0 + tx * 4]) = o;
    }
}

// ---------------- gate logits: softmax/argmax/scatter, fp32 ----------------
// 32 tokens/block, 8 lanes per token. Grid NTOK/32 = 256 blocks.
__global__ __launch_bounds__(256)
void gate_logits_kernel(const float* __restrict__ h, const float* __restrict__ gw2,
                        const float* __restrict__ gb2, const float* __restrict__ ebias,
                        const float* __restrict__ pm_alpha,
                        float* __restrict__ scale, int* __restrict__ counts,
                        int* __restrict__ tlist) {
    __shared__ float hs[32][260];
    __shared__ float g2[GH * NEXP];
    const int tid = threadIdx.x;
    const int t0 = blockIdx.x * 32;
    for (int i = tid; i < GH * NEXP; i += 256) g2[i] = gw2[i];
#pragma unroll
    for (int i = 0; i < 8; ++i) {
        int f4 = i * 256 + tid;                  // float4 index within [32][64]
        int row = f4 >> 6, c4 = (f4 & 63) * 4;
        *reinterpret_cast<float4*>(&hs[row][c4]) =
            *reinterpret_cast<const float4*>(&h[(size_t)(t0 + row) * GH + c4]);
    }
    __syncthreads();
    const int t = tid >> 3, j = tid & 7;
    float p[NEXP] = {0.f, 0.f, 0.f, 0.f, 0.f, 0.f};
    for (int kk = 0; kk < 32; ++kk) {
        int k = j + kk * 8;                      // interleaved: <=2-way LDS banks
        float hv = hs[t][k];
        const float* gr = &g2[k * NEXP];
#pragma unroll
        for (int m = 0; m < NEXP; ++m) p[m] += hv * gr[m];
    }
#pragma unroll
    for (int m = 0; m < NEXP; ++m) {
        p[m] += __shfl_xor(p[m], 4, 64);
        p[m] += __shfl_xor(p[m], 2, 64);
        p[m] += __shfl_xor(p[m], 1, 64);
    }
    if (j == 0) {
        float L[NEXP];
#pragma unroll
        for (int m = 0; m < NEXP; ++m) L[m] = p[m] + gb2[m] + ebias[m];
        float mx = L[0]; int am = 0;
#pragma unroll
        for (int m = 1; m < NEXP; ++m) { if (L[m] > mx) { mx = L[m]; am = m; } }
        float S = 0.f;
#pragma unroll
        for (int m = 0; m < NEXP; ++m) S += expf(L[m] - mx);
        float pt = 1.f / S;
        float w = pt / (pt + 1e-9f);
        scale[t0 + t] = pm_alpha[0] * w;
        int pos = atomicAdd(&counts[am], 1);
        tlist[am * NTOK + pos] = t0 + t;
    }
}

// ---------------- grouped bf16 MFMA GEMM, 64x64 tile, BK=32 -----------------
template <bool GATHER_A, bool EPI_GELU>
__global__ __launch_bounds__(256)
void moe_gemm_kernel(const float* __restrict__ Afp, const short* __restrict__ Abf,
                     const short* __restrict__ Bt, const float* __restrict__ bias,
                     const int* __restrict__ counts, int eidx,
                     const int* __restrict__ tlist, const float* __restrict__ scale,
                     short* __restrict__ Hout, float* __restrict__ Cout,
                     int K, int N) {
    const int n_rows = counts[eidx];
    const int i0 = blockIdx.y * 64;
    if (i0 >= n_rows) return;
    const int rows = min(64, n_rows - i0);
    const int n0 = blockIdx.x * 64;

    __shared__ __align__(16) short As[64 * 40];
    __shared__ __align__(16) short Bs[64 * 40];
    __shared__ int toks[64];
    const int tid = threadIdx.x;
    if (tid < 64) toks[tid] = tlist[eidx * NTOK + i0 + min(tid, rows - 1)];
    __syncthreads();

    f32x4 acc[2][2];
#pragma unroll
    for (int s = 0; s < 2; ++s)
#pragma unroll
        for (int t = 0; t < 2; ++t) acc[s][t] = (f32x4){0.f, 0.f, 0.f, 0.f};

    const int lane = tid & 63, wv = tid >> 6;
    const int wm = (wv & 1) * 32, wn = (wv >> 1) * 32;
    const int lm = lane & 15, q = lane >> 4;
    const int sr = tid >> 2, skg = (tid & 3) * 8;

    for (int k0 = 0; k0 < K; k0 += 32) {
        if constexpr (GATHER_A) {
            const float* src = Afp + (size_t)toks[sr] * K + k0 + skg;
            float4 v0 = *reinterpret_cast<const float4*>(src);
            float4 v1 = *reinterpret_cast<const float4*>(src + 4);
            short tmp[8] = { f2bf(v0.x), f2bf(v0.y), f2bf(v0.z), f2bf(v0.w),
                             f2bf(v1.x), f2bf(v1.y), f2bf(v1.z), f2bf(v1.w) };
            *reinterpret_cast<bf16x8*>(&As[sr * 40 + skg]) = *reinterpret_cast<bf16x8*>(tmp);
        } else {
            int rr = i0 + min(sr, rows - 1);
            *reinterpret_cast<bf16x8*>(&As[sr * 40 + skg]) =
                *reinterpret_cast<const bf16x8*>(&Abf[(size_t)rr * K + k0 + skg]);
        }
        *reinterpret_cast<bf16x8*>(&Bs[sr * 40 + skg]) =
            *reinterpret_cast<const bf16x8*>(&Bt[(size_t)(n0 + sr) * K + k0 + skg]);
        __syncthreads();
        bf16x8 af[2], bfr[2];
#pragma unroll
        for (int s = 0; s < 2; ++s) {
            af[s]  = *reinterpret_cast<bf16x8*>(&As[(wm + s * 16 + lm) * 40 + q * 8]);
            bfr[s] = *reinterpret_cast<bf16x8*>(&Bs[(wn + s * 16 + lm) * 40 + q * 8]);
        }
#pragma unroll
        for (int s = 0; s < 2; ++s)
#pragma unroll
            for (int t = 0; t < 2; ++t)
                acc[s][t] = __builtin_amdgcn_mfma_f32_16x16x32_bf16(af[s], bfr[t], acc[s][t], 0, 0, 0);
        __syncthreads();
    }
#pragma unroll
    for (int s = 0; s < 2; ++s)
#pragma unroll
        for (int t = 0; t < 2; ++t)
#pragma unroll
            for (int rg = 0; rg < 4; ++rg) {
                int rl = wm + s * 16 + q * 4 + rg;
                if (rl < rows) {
                    int gc = n0 + wn + t * 16 + lm;
                    float v = acc[s][t][rg] + bias[gc];
                    if constexpr (EPI_GELU) {
                        Hout[(size_t)(i0 + rl) * N + gc] = f2bf(gelu_erf(v));
                    } else {
                        int tok = toks[rl];
                        Cout[(size_t)tok * N + gc] = scale[tok] * v;
                    }
                }
            }
}

// ---------------- cheap experts (2: rank2, 3: rank4, 4: ReGLU1D, 5: FiLM) ---
__global__ __launch_bounds__(256)
void cheap_experts_kernel(const float* __restrict__ x,
                          const int* __restrict__ counts, const int* __restrict__ tlist,
                          const float* __restrict__ scale,
                          const float* __restrict__ p2_w, const float* __restrict__ p2_v,
                          const float* __restrict__ p2_alpha, const float* __restrict__ p2_b,
                          const float* __restrict__ p2_bias,
                          const float* __restrict__ p4_w, const float* __restrict__ p4_v,
                          const float* __restrict__ p4_alpha, const float* __restrict__ p4_b,
                          const float* __restrict__ p4_bias,
                          const float* __restrict__ rg_u, const float* __restrict__ rg_a,
                          const float* __restrict__ rg_b, const float* __restrict__ rg_bias,
                          const float* __restrict__ fl_dw, const float* __restrict__ fl_db,
                          const float* __restrict__ fl_uw, const float* __restrict__ fl_ub,
                          float* __restrict__ out) {
    const int e = 2 + blockIdx.y;
    const int i = blockIdx.x;
    if (i >= counts[e]) return;
    const int tok = tlist[e * NTOK + i];
    __shared__ float xs[E];
    __shared__ float red[16][4];
    __shared__ float gs[16];
    const int tid = threadIdx.x;
    *reinterpret_cast<float4*>(&xs[tid * 4]) =
        *reinterpret_cast<const float4*>(&x[(size_t)tok * E + tid * 4]);
    __syncthreads();
    const float sc = scale[tok];
    const int lane = tid & 63, wid = tid >> 6;

    if (e == 2 || e == 3) {
        const int n = (e == 2) ? 2 : 4;
        const float* w    = (e == 2) ? p2_w : p4_w;
        const float* v    = (e == 2) ? p2_v : p4_v;
        const float* al   = (e == 2) ? p2_alpha : p4_alpha;
        const float* b    = (e == 2) ? p2_b : p4_b;
        const float* bias = (e == 2) ? p2_bias : p4_bias;
        float p[4] = {0.f, 0.f, 0.f, 0.f};
        for (int k = tid; k < E; k += 256) {
            float xv = xs[k];
            for (int j = 0; j < n; ++j) p[j] += xv * w[j * E + k];
        }
        for (int j = 0; j < n; ++j) {
            float val = p[j];
            for (int off = 32; off > 0; off >>= 1) val += __shfl_down(val, off, 64);
            if (lane == 0) red[j][wid] = val;
        }
        __syncthreads();
        if (tid < n) {
            float s = red[tid][0] + red[tid][1] + red[tid][2] + red[tid][3] + b[tid];
            gs[tid] = al[tid] * gelu_erf(s);
        }
        __syncthreads();
        for (int cx = tid; cx < E; cx += 256) {
            float o = bias[cx];
            for (int j = 0; j < n; ++j) o += gs[j] * v[j * E + cx];
            out[(size_t)tok * E + cx] = sc * o;
        }
    } else if (e == 4) {
        float pv = 0.f;
        for (int k = tid; k < E; k += 256) pv += xs[k] * rg_u[k];
        for (int off = 32; off > 0; off >>= 1) pv += __shfl_down(pv, off, 64);
        if (lane == 0) red[0][wid] = pv;
        __syncthreads();
        float s = red[0][0] + red[0][1] + red[0][2] + red[0][3] + rg_b[0];
        float sg = 1.f / (1.f + expf(-s));
        for (int cx = tid; cx < E; cx += 256)
            out[(size_t)tok * E + cx] = sc * (sg * xs[cx] * rg_a[cx] + rg_bias[cx]);
    } else {  // FiLM
        float p[16];
#pragma unroll
        for (int j = 0; j < 16; ++j) p[j] = 0.f;
        for (int k = tid; k < E; k += 256) {
            float xv = xs[k];
            const float* wr = &fl_dw[k * 16];
#pragma unroll
            for (int j = 0; j < 16; ++j) p[j] += xv * wr[j];
        }
#pragma unroll
        for (int j = 0; j < 16; ++j) {
            float val = p[j];
            for (int off = 32; off > 0; off >>= 1) val += __shfl_down(val, off, 64);
            if (lane == 0) red[j][wid] = val;
        }
        __syncthreads();
        if (tid < 16)
            gs[tid] = gelu_erf(red[tid][0] + red[tid][1] + red[tid][2] + red[tid][3] + fl_db[tid]);
        __syncthreads();
        for (int cx = tid; cx < E; cx += 256) {
            float ga = fl_ub[cx], be = fl_ub[E + cx];
#pragma unroll
            for (int j = 0; j < 16; ++j) {
                float tj = gs[j];
                ga += tj * fl_uw[j * 2 * E + cx];
                be += tj * fl_uw[j * 2 * E + E + cx];
            }
            out[(size_t)tok * E + cx] = sc * (ga * xs[cx] + be);
        }
    }
}

extern "C" void kernel_launch(void* const* d_in, const int* in_sizes, int n_in,
                              void* d_out, int out_size, void* d_ws, size_t ws_size,
                              hipStream_t stream) {
    const float* x        = (const float*)d_in[0];
    const float* gw1      = (const float*)d_in[1];
    const float* gb1      = (const float*)d_in[2];
    const float* gw2      = (const float*)d_in[3];
    const float* gb2      = (const float*)d_in[4];
    const float* ebias    = (const float*)d_in[5];
    const float* pm_alpha = (const float*)d_in[6];
    const float* dfc_w    = (const float*)d_in[7];
    const float* dfc_b    = (const float*)d_in[8];
    const float* dproj_w  = (const float*)d_in[9];
    const float* dproj_b  = (const float*)d_in[10];
    const float* sfc_w    = (const float*)d_in[11];
    const float* sfc_b    = (const float*)d_in[12];
    const float* sproj_w  = (const float*)d_in[13];
    const float* sproj_b  = (const float*)d_in[14];
    const float* p2_w     = (const float*)d_in[15];
    const float* p2_v     = (const float*)d_in[16];
    const float* p2_alpha = (const float*)d_in[17];
    const float* p2_b     = (const float*)d_in[18];
    const float* p2_bias  = (const float*)d_in[19];
    const float* p4_w     = (const float*)d_in[20];
    const float* p4_v     = (const float*)d_in[21];
    const float* p4_alpha = (const float*)d_in[22];
    const float* p4_b     = (const float*)d_in[23];
    const float* p4_bias  = (const float*)d_in[24];
    const float* rg_u     = (const float*)d_in[25];
    const float* rg_a     = (const float*)d_in[26];
    const float* rg_b     = (const float*)d_in[27];
    const float* rg_bias  = (const float*)d_in[28];
    const float* fl_dw    = (const float*)d_in[29];
    const float* fl_db    = (const float*)d_in[30];
    const float* fl_uw    = (const float*)d_in[31];
    const float* fl_ub    = (const float*)d_in[32];
    float* out = (float*)d_out;

    char* ws = (char*)d_ws;
    size_t off = 0;
    int*   counts   = (int*)(ws + off);   off += 256;
    float* scale    = (float*)(ws + off); off += (size_t)NTOK * 4;
    int*   tlist    = (int*)(ws + off);   off += (size_t)NEXP * NTOK * 4;
    short* dfc_wt   = (short*)(ws + off); off += (size_t)2048 * 1024 * 2;
    short* dproj_wt = (short*)(ws + off); off += (size_t)1024 * 2048 * 2;
    short* sfc_wt   = (short*)(ws + off); off += (size_t)1024 * 1024 * 2;
    short* sproj_wt = (short*)(ws + off); off += (size_t)1024 * 1024 * 2;
    short* h1       = (short*)(ws + off); off += (size_t)NTOK * 2048 * 2;
    short* h2       = (short*)(ws + off); off += (size_t)NTOK * 1024 * 2;
    float* h_gate   = (float*)(ws + off); off += (size_t)NTOK * GH * 4;   // ~71.5 MB total

    hipMemsetAsync(counts, 0, 256, stream);
    transpose_bf16_kernel<<<dim3(2048 / 32, 1024 / 32), 256, 0, stream>>>(dfc_w, dfc_wt, 1024, 2048);
    transpose_bf16_kernel<<<dim3(1024 / 32, 2048 / 32), 256, 0, stream>>>(dproj_w, dproj_wt, 2048, 1024);
    transpose_bf16_kernel<<<dim3(1024 / 32, 1024 / 32), 256, 0, stream>>>(sfc_w, sfc_wt, 1024, 1024);
    transpose_bf16_kernel<<<dim3(1024 / 32, 1024 / 32), 256, 0, stream>>>(sproj_w, sproj_wt, 1024, 1024);
    gate_gemm1_kernel<<<dim3(GH / 64, NTOK / 64), 256, 0, stream>>>(x, gw1, gb1, h_gate);
    gate_logits_kernel<<<NTOK / 32, 256, 0, stream>>>(h_gate, gw2, gb2, ebias, pm_alpha,
                                                      scale, counts, tlist);
    moe_gemm_kernel<true, true><<<dim3(2048 / 64, NTOK / 64), 256, 0, stream>>>(
        x, nullptr, dfc_wt, dfc_b, counts, 0, tlist, scale, h1, nullptr, 1024, 2048);
    moe_gemm_kernel<true, true><<<dim3(1024 / 64, NTOK / 64), 256, 0, stream>>>(
        x, nullptr, sfc_wt, sfc_b, counts, 1, tlist, scale, h2, nullptr, 1024, 1024);
    moe_gemm_kernel<false, false><<<dim3(1024 / 64, NTOK / 64), 256, 0, stream>>>(
        nullptr, h1, dproj_wt, dproj_b, counts, 0, tlist, scale, nullptr, out, 2048, 1024);
    moe_gemm_kernel<false, false><<<dim3(1024 / 64, NTOK / 64), 256, 0, stream>>>(
        nullptr, h2, sproj_wt, sproj_b, counts, 1, tlist, scale, nullptr, out, 1024, 1024);
    cheap_experts_kernel<<<dim3(NTOK, 4), 256, 0, stream>>>(
        x, counts, tlist, scale,
        p2_w, p2_v, p2_alpha, p2_b, p2_bias,
        p4_w, p4_v, p4_alpha, p4_b, p4_bias,
        rg_u, rg_a, rg_b, rg_bias,
        fl_dw, fl_db, fl_uw, fl_ub, out);
    (void)in_sizes; (void)n_in; (void)out_size; (void)ws_size;
}

// Round 3
// 424.623 us; speedup vs baseline: 1.0949x; 1.0331x over previous
//
#include <hip/hip_runtime.h>
#include <math.h>

// Top-1 MoE. Gate computed via split-bf16 MFMA (x_hi+x_lo, w_hi+w_lo, 4 cross
// terms as K-concat 4096) -> fp32-accurate logits -> argmax/scatter.
// Experts 0/1: grouped bf16 MFMA GEMMs, m97-style 128x128 tile with
// global_load_lds(16B) staging + XOR bank swizzle. Experts 2-5: cheap kernels.

#define E 1024
#define GH 256
#define NEXP 6
#define NTOK 8192
#define CAP 4096   // per-expert row capacity for h buffers (expected ~1365, 77 sigma margin)

typedef __attribute__((ext_vector_type(8))) short bf16x8;
typedef __attribute__((ext_vector_type(4))) float f32x4;

__device__ __forceinline__ float gelu_erf(float v) {
    return 0.5f * v * (1.0f + erff(v * 0.70710678118654752440f));
}

__device__ __forceinline__ unsigned short f2bf(float f) {
    union { float f; unsigned u; } c; c.f = f;
    unsigned u = c.u;
    u += 0x7fffu + ((u >> 16) & 1u);   // RNE
    return (unsigned short)(u >> 16);
}

__device__ __forceinline__ float bf2f(unsigned short h) {
    union { unsigned u; float f; } c; c.u = ((unsigned)h) << 16;
    return c.f;
}

__device__ __forceinline__ void gload_lds16(const void* g, void* l) {
    __builtin_amdgcn_global_load_lds(
        (const __attribute__((address_space(1))) unsigned int*)g,
        (__attribute__((address_space(3))) unsigned int*)l, 16, 0, 0);
}

// LDS tile addressing (ushort units): row stride 32 (=64B), k-group swizzle.
__device__ __forceinline__ int ldso(int row, int q) {
    return row * 32 + ((q ^ ((row >> 1) & 3)) << 3);
}

// ---------------- x -> x_hi (bf16) + x_lo (bf16 residual) -------------------
__global__ __launch_bounds__(256)
void convert_split_kernel(const float* __restrict__ x, unsigned short* __restrict__ xh,
                          unsigned short* __restrict__ xl, int n4) {
    for (int i = blockIdx.x * 256 + threadIdx.x; i < n4; i += gridDim.x * 256) {
        float4 v = reinterpret_cast<const float4*>(x)[i];
        ushort4 h, l;
        h.x = f2bf(v.x); l.x = f2bf(v.x - bf2f(h.x));
        h.y = f2bf(v.y); l.y = f2bf(v.y - bf2f(h.y));
        h.z = f2bf(v.z); l.z = f2bf(v.z - bf2f(h.z));
        h.w = f2bf(v.w); l.w = f2bf(v.w - bf2f(h.w));
        reinterpret_cast<ushort4*>(xh)[i] = h;
        reinterpret_cast<ushort4*>(xl)[i] = l;
    }
}

// ---------------- weight transpose + fp32->bf16:  src[R][C] -> dst[C][R] ----
__global__ __launch_bounds__(256)
void transpose_bf16_kernel(const float* __restrict__ src, unsigned short* __restrict__ dst,
                           int R, int C) {
    __shared__ float tile[32][33];
    const int tx = threadIdx.x & 31, ty = threadIdx.x >> 5;
    const int c0 = blockIdx.x * 32, r0 = blockIdx.y * 32;
#pragma unroll
    for (int i = 0; i < 4; ++i)
        tile[ty + i * 8][tx] = src[(size_t)(r0 + ty + i * 8) * C + c0 + tx];
    __syncthreads();
#pragma unroll
    for (int i = 0; i < 4; ++i)
        dst[(size_t)(c0 + ty + i * 8) * R + r0 + tx] = f2bf(tile[tx][ty + i * 8]);
}

// ---------------- gw1 transpose + hi/lo split: [E][GH] -> [GH][E] x2 --------
__global__ __launch_bounds__(256)
void transpose_split_kernel(const float* __restrict__ src, unsigned short* __restrict__ dh,
                            unsigned short* __restrict__ dl, int R, int C) {
    __shared__ float tile[32][33];
    const int tx = threadIdx.x & 31, ty = threadIdx.x >> 5;
    const int c0 = blockIdx.x * 32, r0 = blockIdx.y * 32;
#pragma unroll
    for (int i = 0; i < 4; ++i)
        tile[ty + i * 8][tx] = src[(size_t)(r0 + ty + i * 8) * C + c0 + tx];
    __syncthreads();
#pragma unroll
    for (int i = 0; i < 4; ++i) {
        float v = tile[tx][ty + i * 8];
        unsigned short h = f2bf(v);
        dh[(size_t)(c0 + ty + i * 8) * R + r0 + tx] = h;
        dl[(size_t)(c0 + ty + i * 8) * R + r0 + tx] = f2bf(v - bf2f(h));
    }
}

// ---------------- gate GEMM (split-bf16 MFMA, K-concat 4096) ----------------
// M-tile 128, N-tile 64, 4 waves (2x2: 64x32 each). Epilogue: gelu + partial
// logits h@gw2 via fp32 atomics. Grid (GH/64=4, NTOK/128=64).
__global__ __launch_bounds__(256)
void gate_gemm_kernel(const unsigned short* __restrict__ xh, const unsigned short* __restrict__ xl,
                      const unsigned short* __restrict__ wh, const unsigned short* __restrict__ wl,
                      const float* __restrict__ gb1, const float* __restrict__ gw2,
                      float* __restrict__ logits) {
    __shared__ __align__(16) char smem[128 * 65 * 4];   // union: As|Bs then hst
    __shared__ float g2s[64 * 6];
    unsigned short* As = (unsigned short*)smem;          // 128x32
    unsigned short* Bs = As + 128 * 32;                  // 64x32
    float* hst = (float*)smem;                           // [128][65]

    const int tid = threadIdx.x;
    const int t0 = blockIdx.y * 128, n0 = blockIdx.x * 64;
    for (int i = tid; i < 64 * 6; i += 256) g2s[i] = gw2[(size_t)(n0 + i / 6) * NEXP + (i % 6)];

    const int lane = tid & 63, wv = tid >> 6;
    const int wm = (wv & 1) * 64, wn = (wv >> 1) * 32;
    const int lm = lane & 15, q = lane >> 4;
    const int r0 = tid >> 2, gsl = tid & 3;
    const int g = gsl ^ ((r0 >> 1) & 3);      // source k-group for swizzled slot

    f32x4 acc[4][2];
#pragma unroll
    for (int s = 0; s < 4; ++s)
#pragma unroll
        for (int t = 0; t < 2; ++t) acc[s][t] = (f32x4){0.f, 0.f, 0.f, 0.f};

    for (int k0 = 0; k0 < 4096; k0 += 32) {
        const unsigned short* Aseg = (k0 < 2048) ? xh : xl;
        const unsigned short* Bseg = ((k0 >> 10) & 1) ? wl : wh;
        const int kk = (k0 & 1023) + g * 8;
        gload_lds16(Aseg + (size_t)(t0 + r0) * E + kk,       &As[(size_t)tid * 8]);
        gload_lds16(Aseg + (size_t)(t0 + r0 + 64) * E + kk,  &As[2048 + (size_t)tid * 8]);
        gload_lds16(Bseg + (size_t)(n0 + r0) * E + kk,       &Bs[(size_t)tid * 8]);
        __syncthreads();
        bf16x8 af[4], bf[2];
#pragma unroll
        for (int s = 0; s < 4; ++s) af[s] = *(const bf16x8*)&As[ldso(wm + s * 16 + lm, q)];
#pragma unroll
        for (int t = 0; t < 2; ++t) bf[t] = *(const bf16x8*)&Bs[ldso(wn + t * 16 + lm, q)];
#pragma unroll
        for (int s = 0; s < 4; ++s)
#pragma unroll
            for (int t = 0; t < 2; ++t)
                acc[s][t] = __builtin_amdgcn_mfma_f32_16x16x32_bf16(af[s], bf[t], acc[s][t], 0, 0, 0);
        __syncthreads();
    }
    // h tile -> LDS (gelu applied), padded stride 65
#pragma unroll
    for (int s = 0; s < 4; ++s)
#pragma unroll
        for (int t = 0; t < 2; ++t)
#pragma unroll
            for (int rg = 0; rg < 4; ++rg) {
                int rl = wm + s * 16 + q * 4 + rg;
                int c  = wn + t * 16 + lm;
                hst[rl * 65 + c] = gelu_erf(acc[s][t][rg] + gb1[n0 + c]);
            }
    __syncthreads();
    // partial logits: pair of threads per token
    const int tr = tid >> 1, half = tid & 1;
    float p[NEXP] = {0.f, 0.f, 0.f, 0.f, 0.f, 0.f};
#pragma unroll 8
    for (int j = 0; j < 32; ++j) {
        int c = half * 32 + j;
        float hv = hst[tr * 65 + c];
#pragma unroll
        for (int m = 0; m < NEXP; ++m) p[m] += hv * g2s[c * 6 + m];
    }
#pragma unroll
    for (int m = 0; m < NEXP; ++m) p[m] += __shfl_xor(p[m], 1, 64);
    if (half == 0) {
#pragma unroll
        for (int m = 0; m < NEXP; ++m) atomicAdd(&logits[(size_t)(t0 + tr) * NEXP + m], p[m]);
    }
}

// ---------------- finalize: softmax/argmax/scale/scatter --------------------
__global__ __launch_bounds__(256)
void finalize_kernel(const float* __restrict__ logits, const float* __restrict__ gb2,
                     const float* __restrict__ ebias, const float* __restrict__ pm_alpha,
                     float* __restrict__ scale, int* __restrict__ counts,
                     int* __restrict__ tlist) {
    const int t = blockIdx.x * 256 + threadIdx.x;
    if (t >= NTOK) return;
    float L[NEXP];
#pragma unroll
    for (int m = 0; m < NEXP; ++m) L[m] = logits[(size_t)t * NEXP + m] + gb2[m] + ebias[m];
    float mx = L[0]; int am = 0;
#pragma unroll
    for (int m = 1; m < NEXP; ++m) { if (L[m] > mx) { mx = L[m]; am = m; } }
    float S = 0.f;
#pragma unroll
    for (int m = 0; m < NEXP; ++m) S += expf(L[m] - mx);
    float pt = 1.f / S;
    scale[t] = pm_alpha[0] * (pt / (pt + 1e-9f));
    int pos = atomicAdd(&counts[am], 1);
    tlist[am * NTOK + pos] = t;
}

// ---------------- grouped bf16 MFMA GEMM, 128x128 tile, BK=32 ---------------
// z = expert (0/1). GATHER_A: A rows gathered via tlist from x_hi.
// EPI_GELU: gelu->bf16 packed H; else scale+bias -> scatter fp32 Cout.
template <bool GATHER_A, bool EPI_GELU>
__global__ __launch_bounds__(256)
void moe_gemm_kernel(const unsigned short* __restrict__ A0, const unsigned short* __restrict__ A1,
                     const unsigned short* __restrict__ B0, const unsigned short* __restrict__ B1,
                     const float* __restrict__ bias0, const float* __restrict__ bias1,
                     int N0, int N1, int K0, int K1,
                     const int* __restrict__ counts, const int* __restrict__ tlist,
                     const float* __restrict__ scale,
                     unsigned short* __restrict__ H0, unsigned short* __restrict__ H1,
                     float* __restrict__ Cout) {
    const int z = blockIdx.z;
    const int N = z ? N1 : N0, K = z ? K1 : K0;
    const int cnt = counts[z];
    const int i0 = blockIdx.y * 128;
    const int n0 = blockIdx.x * 128;
    if (i0 >= cnt || n0 >= N) return;
    const int rows = min(128, cnt - i0);
    const unsigned short* Az = z ? A1 : A0;
    const unsigned short* Bz = z ? B1 : B0;
    const float* bias = z ? bias1 : bias0;

    __shared__ __align__(16) unsigned short As[128 * 32];
    __shared__ __align__(16) unsigned short Bs[128 * 32];
    __shared__ int toks[128];
    const int tid = threadIdx.x;
    if (tid < 128) toks[tid] = tlist[z * NTOK + min(i0 + tid, cnt - 1)];
    __syncthreads();

    const int lane = tid & 63, wv = tid >> 6;
    const int wm = (wv & 1) * 64, wn = (wv >> 1) * 64;
    const int lm = lane & 15, q = lane >> 4;
    const int r0 = tid >> 2, gsl = tid & 3;
    const int g = gsl ^ ((r0 >> 1) & 3);

    const unsigned short* arow0;
    const unsigned short* arow1;
    if constexpr (GATHER_A) {
        arow0 = Az + (size_t)toks[r0] * K;
        arow1 = Az + (size_t)toks[r0 + 64] * K;
    } else {
        arow0 = Az + (size_t)(i0 + r0) * K;
        arow1 = Az + (size_t)(i0 + r0 + 64) * K;
    }
    const unsigned short* brow0 = Bz + (size_t)(n0 + r0) * K;
    const unsigned short* brow1 = Bz + (size_t)(n0 + r0 + 64) * K;

    f32x4 acc[4][4];
#pragma unroll
    for (int s = 0; s < 4; ++s)
#pragma unroll
        for (int t = 0; t < 4; ++t) acc[s][t] = (f32x4){0.f, 0.f, 0.f, 0.f};

    for (int k0 = 0; k0 < K; k0 += 32) {
        const int kk = k0 + g * 8;
        gload_lds16(arow0 + kk, &As[(size_t)tid * 8]);
        gload_lds16(arow1 + kk, &As[2048 + (size_t)tid * 8]);
        gload_lds16(brow0 + kk, &Bs[(size_t)tid * 8]);
        gload_lds16(brow1 + kk, &Bs[2048 + (size_t)tid * 8]);
        __syncthreads();
        bf16x8 af[4], bf[4];
#pragma unroll
        for (int s = 0; s < 4; ++s) {
            af[s] = *(const bf16x8*)&As[ldso(wm + s * 16 + lm, q)];
            bf[s] = *(const bf16x8*)&Bs[ldso(wn + s * 16 + lm, q)];
        }
#pragma unroll
        for (int s = 0; s < 4; ++s)
#pragma unroll
            for (int t = 0; t < 4; ++t)
                acc[s][t] = __builtin_amdgcn_mfma_f32_16x16x32_bf16(af[s], bf[t], acc[s][t], 0, 0, 0);
        __syncthreads();
    }
    // C/D mapping: col=lane&15, row=(lane>>4)*4+reg
    unsigned short* Hz = z ? H1 : H0;
#pragma unroll
    for (int s = 0; s < 4; ++s)
#pragma unroll
        for (int t = 0; t < 4; ++t)
#pragma unroll
            for (int rg = 0; rg < 4; ++rg) {
                int rl = wm + s * 16 + q * 4 + rg;
                int gc = n0 + wn + t * 16 + lm;
                float v = acc[s][t][rg] + bias[gc];
                if constexpr (EPI_GELU) {
                    Hz[(size_t)(i0 + rl) * N + gc] = f2bf(gelu_erf(v));
                } else {
                    if (rl < rows) {
                        int tok = toks[rl];
                        Cout[(size_t)tok * E + gc] = scale[tok] * v;
                    }
                }
            }
}

// ---------------- cheap experts (2: rank2, 3: rank4, 4: ReGLU1D, 5: FiLM) ---
__global__ __launch_bounds__(256)
void cheap_experts_kernel(const float* __restrict__ x,
                          const int* __restrict__ counts, const int* __restrict__ tlist,
                          const float* __restrict__ scale,
                          const float* __restrict__ p2_w, const float* __restrict__ p2_v,
                          const float* __restrict__ p2_alpha, const float* __restrict__ p2_b,
                          const float* __restrict__ p2_bias,
                          const float* __restrict__ p4_w, const float* __restrict__ p4_v,
                          const float* __restrict__ p4_alpha, const float* __restrict__ p4_b,
                          const float* __restrict__ p4_bias,
                          const float* __restrict__ rg_u, const float* __restrict__ rg_a,
                          const float* __restrict__ rg_b, const float* __restrict__ rg_bias,
                          const float* __restrict__ fl_dw, const float* __restrict__ fl_db,
                          const float* __restrict__ fl_uw, const float* __restrict__ fl_ub,
                          float* __restrict__ out) {
    const int e = 2 + blockIdx.y;
    const int i = blockIdx.x;
    if (i >= counts[e]) return;
    const int tok = tlist[e * NTOK + i];
    __shared__ float xs[E];
    __shared__ float red[16][4];
    __shared__ float gs[16];
    const int tid = threadIdx.x;
    *reinterpret_cast<float4*>(&xs[tid * 4]) =
        *reinterpret_cast<const float4*>(&x[(size_t)tok * E + tid * 4]);
    __syncthreads();
    const float sc = scale[tok];
    const int lane = tid & 63, wid = tid >> 6;

    if (e == 2 || e == 3) {
        const int n = (e == 2) ? 2 : 4;
        const float* w    = (e == 2) ? p2_w : p4_w;
        const float* v    = (e == 2) ? p2_v : p4_v;
        const float* al   = (e == 2) ? p2_alpha : p4_alpha;
        const float* b    = (e == 2) ? p2_b : p4_b;
        const float* bias = (e == 2) ? p2_bias : p4_bias;
        float p[4] = {0.f, 0.f, 0.f, 0.f};
        for (int k = tid; k < E; k += 256) {
            float xv = xs[k];
            for (int j = 0; j < n; ++j) p[j] += xv * w[j * E + k];
        }
        for (int j = 0; j < n; ++j) {
            float val = p[j];
            for (int off = 32; off > 0; off >>= 1) val += __shfl_down(val, off, 64);
            if (lane == 0) red[j][wid] = val;
        }
        __syncthreads();
        if (tid < n) {
            float s = red[tid][0] + red[tid][1] + red[tid][2] + red[tid][3] + b[tid];
            gs[tid] = al[tid] * gelu_erf(s);
        }
        __syncthreads();
        for (int cx = tid; cx < E; cx += 256) {
            float o = bias[cx];
            for (int j = 0; j < n; ++j) o += gs[j] * v[j * E + cx];
            out[(size_t)tok * E + cx] = sc * o;
        }
    } else if (e == 4) {
        float pv = 0.f;
        for (int k = tid; k < E; k += 256) pv += xs[k] * rg_u[k];
        for (int off = 32; off > 0; off >>= 1) pv += __shfl_down(pv, off, 64);
        if (lane == 0) red[0][wid] = pv;
        __syncthreads();
        float s = red[0][0] + red[0][1] + red[0][2] + red[0][3] + rg_b[0];
        float sg = 1.f / (1.f + expf(-s));
        for (int cx = tid; cx < E; cx += 256)
            out[(size_t)tok * E + cx] = sc * (sg * xs[cx] * rg_a[cx] + rg_bias[cx]);
    } else {  // FiLM
        float p[16];
#pragma unroll
        for (int j = 0; j < 16; ++j) p[j] = 0.f;
        for (int k = tid; k < E; k += 256) {
            float xv = xs[k];
            const float* wr = &fl_dw[k * 16];
#pragma unroll
            for (int j = 0; j < 16; ++j) p[j] += xv * wr[j];
        }
#pragma unroll
        for (int j = 0; j < 16; ++j) {
            float val = p[j];
            for (int off = 32; off > 0; off >>= 1) val += __shfl_down(val, off, 64);
            if (lane == 0) red[j][wid] = val;
        }
        __syncthreads();
        if (tid < 16)
            gs[tid] = gelu_erf(red[tid][0] + red[tid][1] + red[tid][2] + red[tid][3] + fl_db[tid]);
        __syncthreads();
        for (int cx = tid; cx < E; cx += 256) {
            float ga = fl_ub[cx], be = fl_ub[E + cx];
#pragma unroll
            for (int j = 0; j < 16; ++j) {
                float tj = gs[j];
                ga += tj * fl_uw[j * 2 * E + cx];
                be += tj * fl_uw[j * 2 * E + E + cx];
            }
            out[(size_t)tok * E + cx] = sc * (ga * xs[cx] + be);
        }
    }
}

extern "C" void kernel_launch(void* const* d_in, const int* in_sizes, int n_in,
                              void* d_out, int out_size, void* d_ws, size_t ws_size,
                              hipStream_t stream) {
    const float* x        = (const float*)d_in[0];
    const float* gw1      = (const float*)d_in[1];
    const float* gb1      = (const float*)d_in[2];
    const float* gw2      = (const float*)d_in[3];
    const float* gb2      = (const float*)d_in[4];
    const float* ebias    = (const float*)d_in[5];
    const float* pm_alpha = (const float*)d_in[6];
    const float* dfc_w    = (const float*)d_in[7];
    const float* dfc_b    = (const float*)d_in[8];
    const float* dproj_w  = (const float*)d_in[9];
    const float* dproj_b  = (const float*)d_in[10];
    const float* sfc_w    = (const float*)d_in[11];
    const float* sfc_b    = (const float*)d_in[12];
    const float* sproj_w  = (const float*)d_in[13];
    const float* sproj_b  = (const float*)d_in[14];
    const float* p2_w     = (const float*)d_in[15];
    const float* p2_v     = (const float*)d_in[16];
    const float* p2_alpha = (const float*)d_in[17];
    const float* p2_b     = (const float*)d_in[18];
    const float* p2_bias  = (const float*)d_in[19];
    const float* p4_w     = (const float*)d_in[20];
    const float* p4_v     = (const float*)d_in[21];
    const float* p4_alpha = (const float*)d_in[22];
    const float* p4_b     = (const float*)d_in[23];
    const float* p4_bias  = (const float*)d_in[24];
    const float* rg_u     = (const float*)d_in[25];
    const float* rg_a     = (const float*)d_in[26];
    const float* rg_b     = (const float*)d_in[27];
    const float* rg_bias  = (const float*)d_in[28];
    const float* fl_dw    = (const float*)d_in[29];
    const float* fl_db    = (const float*)d_in[30];
    const float* fl_uw    = (const float*)d_in[31];
    const float* fl_ub    = (const float*)d_in[32];
    float* out = (float*)d_out;

    char* ws = (char*)d_ws;
    size_t off = 0;
    int*            counts = (int*)(ws + off);            off += 256;
    float*          logits = (float*)(ws + off);          off += (size_t)NTOK * NEXP * 4;
    float*          scale  = (float*)(ws + off);          off += (size_t)NTOK * 4;
    int*            tlist  = (int*)(ws + off);            off += (size_t)NEXP * NTOK * 4;
    unsigned short* w1h    = (unsigned short*)(ws + off); off += (size_t)GH * E * 2;
    unsigned short* w1l    = (unsigned short*)(ws + off); off += (size_t)GH * E * 2;
    unsigned short* dfc_wt = (unsigned short*)(ws + off); off += (size_t)2048 * 1024 * 2;
    unsigned short* dpj_wt = (unsigned short*)(ws + off); off += (size_t)1024 * 2048 * 2;
    unsigned short* sfc_wt = (unsigned short*)(ws + off); off += (size_t)1024 * 1024 * 2;
    unsigned short* spj_wt = (unsigned short*)(ws + off); off += (size_t)1024 * 1024 * 2;
    unsigned short* x_hi   = (unsigned short*)(ws + off); off += (size_t)NTOK * E * 2;
    unsigned short* x_lo   = (unsigned short*)(ws + off); off += (size_t)NTOK * E * 2;
    unsigned short* h1     = (unsigned short*)(ws + off); off += (size_t)CAP * 2048 * 2;
    unsigned short* h2     = (unsigned short*)(ws + off); off += (size_t)CAP * 1024 * 2;  // ~69.7 MB

    hipMemsetAsync(counts, 0, 256 + (size_t)NTOK * NEXP * 4, stream);   // counts + logits
    convert_split_kernel<<<2048, 256, 0, stream>>>(x, x_hi, x_lo, NTOK * E / 4);
    transpose_split_kernel<<<dim3(GH / 32, E / 32), 256, 0, stream>>>(gw1, w1h, w1l, E, GH);
    transpose_bf16_kernel<<<dim3(2048 / 32, 1024 / 32), 256, 0, stream>>>(dfc_w, dfc_wt, 1024, 2048);
    transpose_bf16_kernel<<<dim3(1024 / 32, 2048 / 32), 256, 0, stream>>>(dproj_w, dpj_wt, 2048, 1024);
    transpose_bf16_kernel<<<dim3(1024 / 32, 1024 / 32), 256, 0, stream>>>(sfc_w, sfc_wt, 1024, 1024);
    transpose_bf16_kernel<<<dim3(1024 / 32, 1024 / 32), 256, 0, stream>>>(sproj_w, spj_wt, 1024, 1024);
    gate_gemm_kernel<<<dim3(GH / 64, NTOK / 128), 256, 0, stream>>>(x_hi, x_lo, w1h, w1l,
                                                                    gb1, gw2, logits);
    finalize_kernel<<<NTOK / 256, 256, 0, stream>>>(logits, gb2, ebias, pm_alpha,
                                                    scale, counts, tlist);
    // GEMM1 (gather x_hi -> gelu -> packed h), experts 0/1 merged on z
    moe_gemm_kernel<true, true><<<dim3(16, CAP / 128, 2), 256, 0, stream>>>(
        x_hi, x_hi, dfc_wt, sfc_wt, dfc_b, sfc_b,
        2048, 1024, 1024, 1024, counts, tlist, scale, h1, h2, nullptr);
    // GEMM2 (packed h -> scale+bias -> scatter out), experts 0/1 merged on z
    moe_gemm_kernel<false, false><<<dim3(8, CAP / 128, 2), 256, 0, stream>>>(
        h1, h2, dpj_wt, spj_wt, dproj_b, sproj_b,
        1024, 1024, 2048, 1024, counts, tlist, scale, nullptr, nullptr, out);
    cheap_experts_kernel<<<dim3(NTOK, 4), 256, 0, stream>>>(
        x, counts, tlist, scale,
        p2_w, p2_v, p2_alpha, p2_b, p2_bias,
        p4_w, p4_v, p4_alpha, p4_b, p4_bias,
        rg_u, rg_a, rg_b, rg_bias,
        fl_dw, fl_db, fl_uw, fl_ub, out);
    (void)in_sizes; (void)n_in; (void)out_size; (void)ws_size;
}

// Round 4
// 403.808 us; speedup vs baseline: 1.1513x; 1.0515x over previous
//
#include <hip/hip_runtime.h>
#include <math.h>

// Top-1 MoE. Gate: split-bf16 MFMA (xh+xl)·(wh|wl), split-K over blockIdx.z,
// fp32 partials -> fused gelu/logits/softmax/argmax finalize.
// Experts 0/1: grouped bf16 MFMA GEMMs (128x128, BK=32, VGPR-prefetch dbuf).
// Experts 2-5: cheap per-token kernels.

#define E 1024
#define GH 256
#define NEXP 6
#define NTOK 8192
#define CAP 4096

typedef __attribute__((ext_vector_type(8))) short bf16x8;
typedef __attribute__((ext_vector_type(4))) float f32x4;

__device__ __forceinline__ float gelu_erf(float v) {
    return 0.5f * v * (1.0f + erff(v * 0.70710678118654752440f));
}

__device__ __forceinline__ unsigned short f2bf(float f) {
    union { float f; unsigned u; } c; c.f = f;
    unsigned u = c.u;
    u += 0x7fffu + ((u >> 16) & 1u);   // RNE
    return (unsigned short)(u >> 16);
}

__device__ __forceinline__ float bf2f(unsigned short h) {
    union { unsigned u; float f; } c; c.u = ((unsigned)h) << 16;
    return c.f;
}

// LDS tile addressing (ushort units): row stride 32 (=64B), k-group XOR swizzle.
__device__ __forceinline__ int ldso(int row, int q) {
    return row * 32 + ((q ^ ((row >> 1) & 3)) << 3);
}

// ---------------- x -> x_hi (bf16) + x_lo (bf16 residual) -------------------
__global__ __launch_bounds__(256)
void convert_split_kernel(const float* __restrict__ x, unsigned short* __restrict__ xh,
                          unsigned short* __restrict__ xl, int n4) {
    for (int i = blockIdx.x * 256 + threadIdx.x; i < n4; i += gridDim.x * 256) {
        float4 v = reinterpret_cast<const float4*>(x)[i];
        ushort4 h, l;
        h.x = f2bf(v.x); l.x = f2bf(v.x - bf2f(h.x));
        h.y = f2bf(v.y); l.y = f2bf(v.y - bf2f(h.y));
        h.z = f2bf(v.z); l.z = f2bf(v.z - bf2f(h.z));
        h.w = f2bf(v.w); l.w = f2bf(v.w - bf2f(h.w));
        reinterpret_cast<ushort4*>(xh)[i] = h;
        reinterpret_cast<ushort4*>(xl)[i] = l;
    }
}

// ---------------- weight transpose + fp32->bf16:  src[R][C] -> dst[C][R] ----
__global__ __launch_bounds__(256)
void transpose_bf16_kernel(const float* __restrict__ src, unsigned short* __restrict__ dst,
                           int R, int C) {
    __shared__ float tile[32][33];
    const int tx = threadIdx.x & 31, ty = threadIdx.x >> 5;
    const int c0 = blockIdx.x * 32, r0 = blockIdx.y * 32;
#pragma unroll
    for (int i = 0; i < 4; ++i)
        tile[ty + i * 8][tx] = src[(size_t)(r0 + ty + i * 8) * C + c0 + tx];
    __syncthreads();
#pragma unroll
    for (int i = 0; i < 4; ++i)
        dst[(size_t)(c0 + ty + i * 8) * R + r0 + tx] = f2bf(tile[tx][ty + i * 8]);
}

// ------- gw1 [E][GH] -> w1cat [GH][2048]: cols 0..1023 = hi, 1024.. = lo ----
__global__ __launch_bounds__(256)
void transpose_split_kernel(const float* __restrict__ src, unsigned short* __restrict__ dcat) {
    __shared__ float tile[32][33];
    const int tx = threadIdx.x & 31, ty = threadIdx.x >> 5;
    const int c0 = blockIdx.x * 32, r0 = blockIdx.y * 32;   // c over GH, r over E
#pragma unroll
    for (int i = 0; i < 4; ++i)
        tile[ty + i * 8][tx] = src[(size_t)(r0 + ty + i * 8) * GH + c0 + tx];
    __syncthreads();
#pragma unroll
    for (int i = 0; i < 4; ++i) {
        float v = tile[tx][ty + i * 8];
        unsigned short h = f2bf(v);
        size_t row = (size_t)(c0 + ty + i * 8) * 2048;
        dcat[row + r0 + tx] = h;
        dcat[row + 1024 + r0 + tx] = f2bf(v - bf2f(h));
    }
}

// ---------------- gate partial GEMM: hp_z = A_z @ w1cat, fp32 ---------------
// M=128, N=64, K=2048 (64 iters), A = z ? x_lo : x_hi (k mod 1024).
// Grid (GH/64=4, NTOK/128=64, 2) = 512 blocks. VGPR-prefetch double buffer.
__global__ __launch_bounds__(256)
void gate_partial_kernel(const unsigned short* __restrict__ xh,
                         const unsigned short* __restrict__ xl,
                         const unsigned short* __restrict__ w1cat,
                         float* __restrict__ hp0, float* __restrict__ hp1) {
    __shared__ __align__(16) unsigned short As[128 * 32];
    __shared__ __align__(16) unsigned short Bs[64 * 32];
    const int tid = threadIdx.x;
    const int t0 = blockIdx.y * 128, n0 = blockIdx.x * 64, z = blockIdx.z;
    const unsigned short* A = z ? xl : xh;
    float* hp = z ? hp1 : hp0;

    const int lane = tid & 63, wv = tid >> 6;
    const int wm = (wv & 1) * 64, wn = (wv >> 1) * 32;
    const int lm = lane & 15, q = lane >> 4;
    const int r0 = tid >> 2, gsl = tid & 3;
    const int g = gsl ^ ((r0 >> 1) & 3);

    const unsigned short* pa0 = A + (size_t)(t0 + r0) * E + g * 8;
    const unsigned short* pa1 = A + (size_t)(t0 + r0 + 64) * E + g * 8;
    const unsigned short* pb0 = w1cat + (size_t)(n0 + r0) * 2048 + g * 8;

    f32x4 acc[4][2];
#pragma unroll
    for (int s = 0; s < 4; ++s)
#pragma unroll
        for (int t = 0; t < 2; ++t) acc[s][t] = (f32x4){0.f, 0.f, 0.f, 0.f};

    bf16x8 ra0 = *(const bf16x8*)(pa0);
    bf16x8 ra1 = *(const bf16x8*)(pa1);
    bf16x8 rb0 = *(const bf16x8*)(pb0);
    *(bf16x8*)&As[r0 * 32 + gsl * 8] = ra0;
    *(bf16x8*)&As[(r0 + 64) * 32 + gsl * 8] = ra1;
    *(bf16x8*)&Bs[r0 * 32 + gsl * 8] = rb0;   // r0<64 rows valid; r0>=64 writes As rows? no: r0<=63
    // NOTE: r0 ranges 0..63 (tid>>2), so Bs indexing is in range.

    int k0 = 0;
    while (true) {
        __syncthreads();
        const int kn = k0 + 32;
        if (kn < 2048) {
            ra0 = *(const bf16x8*)(pa0 + (kn & 1023));
            ra1 = *(const bf16x8*)(pa1 + (kn & 1023));
            rb0 = *(const bf16x8*)(pb0 + kn);
        }
        bf16x8 af[4], bf[2];
#pragma unroll
        for (int s = 0; s < 4; ++s) af[s] = *(const bf16x8*)&As[ldso(wm + s * 16 + lm, q)];
#pragma unroll
        for (int t = 0; t < 2; ++t) bf[t] = *(const bf16x8*)&Bs[ldso(wn + t * 16 + lm, q)];
#pragma unroll
        for (int s = 0; s < 4; ++s)
#pragma unroll
            for (int t = 0; t < 2; ++t)
                acc[s][t] = __builtin_amdgcn_mfma_f32_16x16x32_bf16(af[s], bf[t], acc[s][t], 0, 0, 0);
        if (kn >= 2048) break;
        __syncthreads();
        *(bf16x8*)&As[r0 * 32 + gsl * 8] = ra0;
        *(bf16x8*)&As[(r0 + 64) * 32 + gsl * 8] = ra1;
        *(bf16x8*)&Bs[r0 * 32 + gsl * 8] = rb0;
        k0 = kn;
    }
    // C/D: col=lane&15, row=(lane>>4)*4+reg
#pragma unroll
    for (int s = 0; s < 4; ++s)
#pragma unroll
        for (int t = 0; t < 2; ++t)
#pragma unroll
            for (int rg = 0; rg < 4; ++rg) {
                int rl = wm + s * 16 + q * 4 + rg;
                int c  = wn + t * 16 + lm;
                hp[(size_t)(t0 + rl) * GH + n0 + c] = acc[s][t][rg];
            }
}

// ------- finalize: h=gelu(hp0+hp1+gb1); logits=h@gw2; softmax/argmax --------
// 32 tokens/block, 8 lanes/token. Grid NTOK/32 = 256 blocks.
__global__ __launch_bounds__(256)
void gate_finalize_kernel(const float* __restrict__ hp0, const float* __restrict__ hp1,
                          const float* __restrict__ gb1, const float* __restrict__ gw2,
                          const float* __restrict__ gb2, const float* __restrict__ ebias,
                          const float* __restrict__ pm_alpha,
                          float* __restrict__ scale, int* __restrict__ counts,
                          int* __restrict__ tlist) {
    __shared__ float hs[32][264];
    __shared__ float g2s[GH * NEXP];
    const int tid = threadIdx.x;
    const int t0 = blockIdx.x * 32;
    for (int i = tid; i < GH * NEXP; i += 256) g2s[i] = gw2[i];
#pragma unroll
    for (int i = 0; i < 8; ++i) {
        int f4 = i * 256 + tid;                  // [32][64] float4 tiles
        int row = f4 >> 6, c4 = (f4 & 63) * 4;
        size_t base = (size_t)(t0 + row) * GH + c4;
        float4 a = *reinterpret_cast<const float4*>(&hp0[base]);
        float4 b = *reinterpret_cast<const float4*>(&hp1[base]);
        float4 o;
        o.x = gelu_erf(a.x + b.x + gb1[c4 + 0]);
        o.y = gelu_erf(a.y + b.y + gb1[c4 + 1]);
        o.z = gelu_erf(a.z + b.z + gb1[c4 + 2]);
        o.w = gelu_erf(a.w + b.w + gb1[c4 + 3]);
        *reinterpret_cast<float4*>(&hs[row][c4]) = o;
    }
    __syncthreads();
    const int t = tid >> 3, j = tid & 7;
    float p[NEXP] = {0.f, 0.f, 0.f, 0.f, 0.f, 0.f};
#pragma unroll 8
    for (int kk = 0; kk < 32; ++kk) {
        int k = j + kk * 8;                      // 6j bank offsets: conflict-free
        float hv = hs[t][k];
        const float* gr = &g2s[k * NEXP];
#pragma unroll
        for (int m = 0; m < NEXP; ++m) p[m] += hv * gr[m];
    }
#pragma unroll
    for (int m = 0; m < NEXP; ++m) {
        p[m] += __shfl_xor(p[m], 4, 64);
        p[m] += __shfl_xor(p[m], 2, 64);
        p[m] += __shfl_xor(p[m], 1, 64);
    }
    if (j == 0) {
        float L[NEXP];
#pragma unroll
        for (int m = 0; m < NEXP; ++m) L[m] = p[m] + gb2[m] + ebias[m];
        float mx = L[0]; int am = 0;
#pragma unroll
        for (int m = 1; m < NEXP; ++m) { if (L[m] > mx) { mx = L[m]; am = m; } }
        float S = 0.f;
#pragma unroll
        for (int m = 0; m < NEXP; ++m) S += expf(L[m] - mx);
        float pt = 1.f / S;
        scale[t0 + t] = pm_alpha[0] * (pt / (pt + 1e-9f));
        int pos = atomicAdd(&counts[am], 1);
        tlist[am * NTOK + pos] = t0 + t;
    }
}

// ---------------- grouped bf16 MFMA GEMM, 128x128 tile, BK=32 ---------------
// VGPR-prefetch double buffer. z = expert (0/1).
template <bool GATHER_A, bool EPI_GELU>
__global__ __launch_bounds__(256)
void moe_gemm_kernel(const unsigned short* __restrict__ A0, const unsigned short* __restrict__ A1,
                     const unsigned short* __restrict__ B0, const unsigned short* __restrict__ B1,
                     const float* __restrict__ bias0, const float* __restrict__ bias1,
                     int N0, int N1, int K0, int K1,
                     const int* __restrict__ counts, const int* __restrict__ tlist,
                     const float* __restrict__ scale,
                     unsigned short* __restrict__ H0, unsigned short* __restrict__ H1,
                     float* __restrict__ Cout) {
    const int z = blockIdx.z;
    const int N = z ? N1 : N0, K = z ? K1 : K0;
    const int cnt = counts[z];
    const int i0 = blockIdx.y * 128;
    const int n0 = blockIdx.x * 128;
    if (i0 >= cnt || n0 >= N) return;
    const int rows = min(128, cnt - i0);
    const unsigned short* Az = z ? A1 : A0;
    const unsigned short* Bz = z ? B1 : B0;
    const float* bias = z ? bias1 : bias0;

    __shared__ __align__(16) unsigned short As[128 * 32];
    __shared__ __align__(16) unsigned short Bs[128 * 32];
    __shared__ int toks[128];
    const int tid = threadIdx.x;
    if (tid < 128) toks[tid] = tlist[z * NTOK + min(i0 + tid, cnt - 1)];
    __syncthreads();

    const int lane = tid & 63, wv = tid >> 6;
    const int wm = (wv & 1) * 64, wn = (wv >> 1) * 64;
    const int lm = lane & 15, q = lane >> 4;
    const int r0 = tid >> 2, gsl = tid & 3;
    const int g = gsl ^ ((r0 >> 1) & 3);

    const unsigned short* pa0;
    const unsigned short* pa1;
    if constexpr (GATHER_A) {
        pa0 = Az + (size_t)toks[r0] * K + g * 8;
        pa1 = Az + (size_t)toks[r0 + 64] * K + g * 8;
    } else {
        pa0 = Az + (size_t)(i0 + r0) * K + g * 8;
        pa1 = Az + (size_t)(i0 + r0 + 64) * K + g * 8;
    }
    const unsigned short* pb0 = Bz + (size_t)(n0 + r0) * K + g * 8;
    const unsigned short* pb1 = Bz + (size_t)(n0 + r0 + 64) * K + g * 8;

    f32x4 acc[4][4];
#pragma unroll
    for (int s = 0; s < 4; ++s)
#pragma unroll
        for (int t = 0; t < 4; ++t) acc[s][t] = (f32x4){0.f, 0.f, 0.f, 0.f};

    bf16x8 ra0 = *(const bf16x8*)(pa0);
    bf16x8 ra1 = *(const bf16x8*)(pa1);
    bf16x8 rb0 = *(const bf16x8*)(pb0);
    bf16x8 rb1 = *(const bf16x8*)(pb1);
    *(bf16x8*)&As[r0 * 32 + gsl * 8] = ra0;
    *(bf16x8*)&As[(r0 + 64) * 32 + gsl * 8] = ra1;
    *(bf16x8*)&Bs[r0 * 32 + gsl * 8] = rb0;
    *(bf16x8*)&Bs[(r0 + 64) * 32 + gsl * 8] = rb1;

    int k0 = 0;
    while (true) {
        __syncthreads();
        const int kn = k0 + 32;
        if (kn < K) {
            ra0 = *(const bf16x8*)(pa0 + kn);
            ra1 = *(const bf16x8*)(pa1 + kn);
            rb0 = *(const bf16x8*)(pb0 + kn);
            rb1 = *(const bf16x8*)(pb1 + kn);
        }
        bf16x8 af[4], bf[4];
#pragma unroll
        for (int s = 0; s < 4; ++s) {
            af[s] = *(const bf16x8*)&As[ldso(wm + s * 16 + lm, q)];
            bf[s] = *(const bf16x8*)&Bs[ldso(wn + s * 16 + lm, q)];
        }
#pragma unroll
        for (int s = 0; s < 4; ++s)
#pragma unroll
            for (int t = 0; t < 4; ++t)
                acc[s][t] = __builtin_amdgcn_mfma_f32_16x16x32_bf16(af[s], bf[t], acc[s][t], 0, 0, 0);
        if (kn >= K) break;
        __syncthreads();
        *(bf16x8*)&As[r0 * 32 + gsl * 8] = ra0;
        *(bf16x8*)&As[(r0 + 64) * 32 + gsl * 8] = ra1;
        *(bf16x8*)&Bs[r0 * 32 + gsl * 8] = rb0;
        *(bf16x8*)&Bs[(r0 + 64) * 32 + gsl * 8] = rb1;
        k0 = kn;
    }
    // C/D mapping: col=lane&15, row=(lane>>4)*4+reg
    unsigned short* Hz = z ? H1 : H0;
#pragma unroll
    for (int s = 0; s < 4; ++s)
#pragma unroll
        for (int t = 0; t < 4; ++t)
#pragma unroll
            for (int rg = 0; rg < 4; ++rg) {
                int rl = wm + s * 16 + q * 4 + rg;
                int gc = n0 + wn + t * 16 + lm;
                float v = acc[s][t][rg] + bias[gc];
                if constexpr (EPI_GELU) {
                    Hz[(size_t)(i0 + rl) * N + gc] = f2bf(gelu_erf(v));
                } else {
                    if (rl < rows) {
                        int tok = toks[rl];
                        Cout[(size_t)tok * E + gc] = scale[tok] * v;
                    }
                }
            }
}

// ---------------- cheap experts (2: rank2, 3: rank4, 4: ReGLU1D, 5: FiLM) ---
__global__ __launch_bounds__(256)
void cheap_experts_kernel(const float* __restrict__ x,
                          const int* __restrict__ counts, const int* __restrict__ tlist,
                          const float* __restrict__ scale,
                          const float* __restrict__ p2_w, const float* __restrict__ p2_v,
                          const float* __restrict__ p2_alpha, const float* __restrict__ p2_b,
                          const float* __restrict__ p2_bias,
                          const float* __restrict__ p4_w, const float* __restrict__ p4_v,
                          const float* __restrict__ p4_alpha, const float* __restrict__ p4_b,
                          const float* __restrict__ p4_bias,
                          const float* __restrict__ rg_u, const float* __restrict__ rg_a,
                          const float* __restrict__ rg_b, const float* __restrict__ rg_bias,
                          const float* __restrict__ fl_dw, const float* __restrict__ fl_db,
                          const float* __restrict__ fl_uw, const float* __restrict__ fl_ub,
                          float* __restrict__ out) {
    const int e = 2 + blockIdx.y;
    const int i = blockIdx.x;
    if (i >= counts[e]) return;
    const int tok = tlist[e * NTOK + i];
    __shared__ float xs[E];
    __shared__ float red[16][4];
    __shared__ float gs[16];
    const int tid = threadIdx.x;
    *reinterpret_cast<float4*>(&xs[tid * 4]) =
        *reinterpret_cast<const float4*>(&x[(size_t)tok * E + tid * 4]);
    __syncthreads();
    const float sc = scale[tok];
    const int lane = tid & 63, wid = tid >> 6;

    if (e == 2 || e == 3) {
        const int n = (e == 2) ? 2 : 4;
        const float* w    = (e == 2) ? p2_w : p4_w;
        const float* v    = (e == 2) ? p2_v : p4_v;
        const float* al   = (e == 2) ? p2_alpha : p4_alpha;
        const float* b    = (e == 2) ? p2_b : p4_b;
        const float* bias = (e == 2) ? p2_bias : p4_bias;
        float p[4] = {0.f, 0.f, 0.f, 0.f};
        for (int k = tid; k < E; k += 256) {
            float xv = xs[k];
            for (int j = 0; j < n; ++j) p[j] += xv * w[j * E + k];
        }
        for (int j = 0; j < n; ++j) {
            float val = p[j];
            for (int off = 32; off > 0; off >>= 1) val += __shfl_down(val, off, 64);
            if (lane == 0) red[j][wid] = val;
        }
        __syncthreads();
        if (tid < n) {
            float s = red[tid][0] + red[tid][1] + red[tid][2] + red[tid][3] + b[tid];
            gs[tid] = al[tid] * gelu_erf(s);
        }
        __syncthreads();
        for (int cx = tid; cx < E; cx += 256) {
            float o = bias[cx];
            for (int j = 0; j < n; ++j) o += gs[j] * v[j * E + cx];
            out[(size_t)tok * E + cx] = sc * o;
        }
    } else if (e == 4) {
        float pv = 0.f;
        for (int k = tid; k < E; k += 256) pv += xs[k] * rg_u[k];
        for (int off = 32; off > 0; off >>= 1) pv += __shfl_down(pv, off, 64);
        if (lane == 0) red[0][wid] = pv;
        __syncthreads();
        float s = red[0][0] + red[0][1] + red[0][2] + red[0][3] + rg_b[0];
        float sg = 1.f / (1.f + expf(-s));
        for (int cx = tid; cx < E; cx += 256)
            out[(size_t)tok * E + cx] = sc * (sg * xs[cx] * rg_a[cx] + rg_bias[cx]);
    } else {  // FiLM
        float p[16];
#pragma unroll
        for (int j = 0; j < 16; ++j) p[j] = 0.f;
        for (int k = tid; k < E; k += 256) {
            float xv = xs[k];
            const float* wr = &fl_dw[k * 16];
#pragma unroll
            for (int j = 0; j < 16; ++j) p[j] += xv * wr[j];
        }
#pragma unroll
        for (int j = 0; j < 16; ++j) {
            float val = p[j];
            for (int off = 32; off > 0; off >>= 1) val += __shfl_down(val, off, 64);
            if (lane == 0) red[j][wid] = val;
        }
        __syncthreads();
        if (tid < 16)
            gs[tid] = gelu_erf(red[tid][0] + red[tid][1] + red[tid][2] + red[tid][3] + fl_db[tid]);
        __syncthreads();
        for (int cx = tid; cx < E; cx += 256) {
            float ga = fl_ub[cx], be = fl_ub[E + cx];
#pragma unroll
            for (int j = 0; j < 16; ++j) {
                float tj = gs[j];
                ga += tj * fl_uw[j * 2 * E + cx];
                be += tj * fl_uw[j * 2 * E + E + cx];
            }
            out[(size_t)tok * E + cx] = sc * (ga * xs[cx] + be);
        }
    }
}

extern "C" void kernel_launch(void* const* d_in, const int* in_sizes, int n_in,
                              void* d_out, int out_size, void* d_ws, size_t ws_size,
                              hipStream_t stream) {
    const float* x        = (const float*)d_in[0];
    const float* gw1      = (const float*)d_in[1];
    const float* gb1      = (const float*)d_in[2];
    const float* gw2      = (const float*)d_in[3];
    const float* gb2      = (const float*)d_in[4];
    const float* ebias    = (const float*)d_in[5];
    const float* pm_alpha = (const float*)d_in[6];
    const float* dfc_w    = (const float*)d_in[7];
    const float* dfc_b    = (const float*)d_in[8];
    const float* dproj_w  = (const float*)d_in[9];
    const float* dproj_b  = (const float*)d_in[10];
    const float* sfc_w    = (const float*)d_in[11];
    const float* sfc_b    = (const float*)d_in[12];
    const float* sproj_w  = (const float*)d_in[13];
    const float* sproj_b  = (const float*)d_in[14];
    const float* p2_w     = (const float*)d_in[15];
    const float* p2_v     = (const float*)d_in[16];
    const float* p2_alpha = (const float*)d_in[17];
    const float* p2_b     = (const float*)d_in[18];
    const float* p2_bias  = (const float*)d_in[19];
    const float* p4_w     = (const float*)d_in[20];
    const float* p4_v     = (const float*)d_in[21];
    const float* p4_alpha = (const float*)d_in[22];
    const float* p4_b     = (const float*)d_in[23];
    const float* p4_bias  = (const float*)d_in[24];
    const float* rg_u     = (const float*)d_in[25];
    const float* rg_a     = (const float*)d_in[26];
    const float* rg_b     = (const float*)d_in[27];
    const float* rg_bias  = (const float*)d_in[28];
    const float* fl_dw    = (const float*)d_in[29];
    const float* fl_db    = (const float*)d_in[30];
    const float* fl_uw    = (const float*)d_in[31];
    const float* fl_ub    = (const float*)d_in[32];
    float* out = (float*)d_out;

    char* ws = (char*)d_ws;
    size_t off = 0;
    int*            counts = (int*)(ws + off);            off += 256;
    float*          scale  = (float*)(ws + off);          off += (size_t)NTOK * 4;
    int*            tlist  = (int*)(ws + off);            off += (size_t)NEXP * NTOK * 4;
    unsigned short* w1cat  = (unsigned short*)(ws + off); off += (size_t)GH * 2048 * 2;
    unsigned short* dfc_wt = (unsigned short*)(ws + off); off += (size_t)2048 * 1024 * 2;
    unsigned short* dpj_wt = (unsigned short*)(ws + off); off += (size_t)1024 * 2048 * 2;
    unsigned short* sfc_wt = (unsigned short*)(ws + off); off += (size_t)1024 * 1024 * 2;
    unsigned short* spj_wt = (unsigned short*)(ws + off); off += (size_t)1024 * 1024 * 2;
    unsigned short* x_hi   = (unsigned short*)(ws + off); off += (size_t)NTOK * E * 2;
    // Union region (32 MB): gate phase {x_lo, hp0, hp1} then expert phase {h1, h2}
    char* U = ws + off;
    unsigned short* x_lo = (unsigned short*)U;                          // 16 MB
    float*          hp0  = (float*)(U + (size_t)16 * 1024 * 1024);      // 8 MB
    float*          hp1  = (float*)(U + (size_t)24 * 1024 * 1024);      // 8 MB
    unsigned short* h1   = (unsigned short*)U;                          // 16 MB (CAP x 2048)
    unsigned short* h2   = (unsigned short*)(U + (size_t)16 * 1024 * 1024); // 8 MB (CAP x 1024)
    // total ~61.3 MB

    hipMemsetAsync(counts, 0, 256, stream);
    convert_split_kernel<<<2048, 256, 0, stream>>>(x, x_hi, x_lo, NTOK * E / 4);
    transpose_split_kernel<<<dim3(GH / 32, E / 32), 256, 0, stream>>>(gw1, w1cat);
    transpose_bf16_kernel<<<dim3(2048 / 32, 1024 / 32), 256, 0, stream>>>(dfc_w, dfc_wt, 1024, 2048);
    transpose_bf16_kernel<<<dim3(1024 / 32, 2048 / 32), 256, 0, stream>>>(dproj_w, dpj_wt, 2048, 1024);
    transpose_bf16_kernel<<<dim3(1024 / 32, 1024 / 32), 256, 0, stream>>>(sfc_w, sfc_wt, 1024, 1024);
    transpose_bf16_kernel<<<dim3(1024 / 32, 1024 / 32), 256, 0, stream>>>(sproj_w, spj_wt, 1024, 1024);
    gate_partial_kernel<<<dim3(GH / 64, NTOK / 128, 2), 256, 0, stream>>>(x_hi, x_lo, w1cat, hp0, hp1);
    gate_finalize_kernel<<<NTOK / 32, 256, 0, stream>>>(hp0, hp1, gb1, gw2, gb2, ebias,
                                                        pm_alpha, scale, counts, tlist);
    moe_gemm_kernel<true, true><<<dim3(16, CAP / 128, 2), 256, 0, stream>>>(
        x_hi, x_hi, dfc_wt, sfc_wt, dfc_b, sfc_b,
        2048, 1024, 1024, 1024, counts, tlist, scale, h1, h2, nullptr);
    moe_gemm_kernel<false, false><<<dim3(8, CAP / 128, 2), 256, 0, stream>>>(
        h1, h2, dpj_wt, spj_wt, dproj_b, sproj_b,
        1024, 1024, 2048, 1024, counts, tlist, scale, nullptr, nullptr, out);
    cheap_experts_kernel<<<dim3(NTOK, 4), 256, 0, stream>>>(
        x, counts, tlist, scale,
        p2_w, p2_v, p2_alpha, p2_b, p2_bias,
        p4_w, p4_v, p4_alpha, p4_b, p4_bias,
        rg_u, rg_a, rg_b, rg_bias,
        fl_dw, fl_db, fl_uw, fl_ub, out);
    (void)in_sizes; (void)n_in; (void)out_size; (void)ws_size;
}